// Round 12
// baseline (108.835 us; speedup 1.0000x reference)
//
#include <hip/hip_runtime.h>
#include <stdint.h>

// Problem constants
constexpr int NB   = 32;     // batch
constexpr int LLEN = 1024;   // max wordpiece len
constexpr int DDIM = 768;    // hidden
constexpr int CCH  = 256;    // max chunks
constexpr int KMAX = 8;      // max chunk len
constexpr int KTOT = 3 * DDIM;   // 2304 reduction dim (3 taps x D)

// GEMM tiling
constexpr int BM = 128;
constexpr int BN = 128;
constexpr int BK = 64;
constexpr int NKS = KTOT / BK;       // 36 k-steps
constexpr int NTILE = DDIM / BN;     // 6 col tiles
constexpr int NRB = NB * LLEN / BM;  // 256 row blocks

// ws layout (bytes)
constexpr size_t FLAGS_OFF = 0;
constexpr size_t FLAGS_SZ  = (size_t)NB * LLEN * sizeof(int);           // 128 KB
constexpr size_t WP_OFF    = FLAGS_OFF + FLAGS_SZ;
constexpr size_t WP_SZ     = (size_t)NTILE * NKS * BN * BK * 2;         // 3.456 MB
constexpr size_t ZP_OFF    = WP_OFF + WP_SZ;
constexpr size_t ZP_SZ     = 256;
constexpr size_t FB_OFF    = ZP_OFF + ZP_SZ;
constexpr size_t FB_SZ     = (size_t)NB * LLEN * DDIM * 2;              // 50.33 MB
constexpr size_t WS_NEED   = FB_OFF + FB_SZ;

typedef __attribute__((ext_vector_type(4))) float f32x4;
typedef __attribute__((ext_vector_type(16))) float f32x16;
typedef __bf16 bf16x8 __attribute__((ext_vector_type(8)));

__device__ inline unsigned short f2bf(float f) {
    unsigned u = __float_as_uint(f);
    u = u + 0x7FFFu + ((u >> 16) & 1u);   // round-to-nearest-even
    return (unsigned short)(u >> 16);
}

__device__ inline void gload_lds16(const void* g, void* l) {
    __builtin_amdgcn_global_load_lds(
        (const __attribute__((address_space(1))) unsigned int*)g,
        (__attribute__((address_space(3))) unsigned int*)l, 16, 0, 0);
}

// ---------------- kernel 1: per-row flags from chunk_lens ----------------
// flags[b*L + p] : bit0 = valid, bit1 = has_left (k>0), bit2 = has_right (k+1<trunc)
__global__ void meta_kernel(const int* __restrict__ chunk_lens, int* __restrict__ flags) {
    int b = blockIdx.x, tid = threadIdx.x;   // blockDim = 256 == CCH
    __shared__ int s[CCH];
    int len = chunk_lens[b * CCH + tid];
    s[tid] = len;
    __syncthreads();
    for (int off = 1; off < CCH; off <<= 1) {
        int v = (tid >= off) ? s[tid - off] : 0;
        __syncthreads();
        s[tid] += v;
        __syncthreads();
    }
    int start = s[tid] - len;   // exclusive cumsum
    for (int i = tid; i < LLEN; i += CCH) flags[b * LLEN + i] = 0;
    __syncthreads();
    int t = min(len, KMAX);
    for (int k = 0; k < t; ++k) {
        int p = start + k;
        if (p < LLEN)
            flags[b * LLEN + p] = 1 | (k > 0 ? 2 : 0) | (k + 1 < t ? 4 : 0);
    }
}

// ---------------- kernel 2: pack conv_w -> bf16 swizzled B images (vectorized) ----
// R9/R11-verified. One thread emits 8 contiguous swizzled elements (the XOR
// permutes 8-element granules) = one dwordx4 store. Last block zeroes the zeropage.
__global__ void packw2_kernel(const float* __restrict__ conv_w, unsigned short* __restrict__ Wp,
                              unsigned int* __restrict__ zeropage) {
    if (blockIdx.x == gridDim.x - 1) {
        if (threadIdx.x < (int)(ZP_SZ / 4)) zeropage[threadIdx.x] = 0u;
        return;
    }
    int idx = blockIdx.x * 256 + threadIdx.x;   // [0, 6*36*128*8 = 221184)
    if (idx >= NTILE * NKS * BN * 8) return;
    int m    = idx & 7;
    int nl   = (idx >> 3) & (BN - 1);
    int rest = idx >> 10;             // nt*NKS + ks in [0,216)
    int ks   = rest % NKS;
    int nt   = rest / NKS;
    int n    = nt * BN + nl;
    int k0   = ks * BK + m * 8;       // 8-run never crosses a tap boundary (768%64==0)
    int tap  = k0 / DDIM;
    int i0   = k0 % DDIM;
    const float* src = conv_w + ((size_t)n * DDIM + i0) * 3 + tap;  // stride-3 gather
    unsigned wrds[4];
    #pragma unroll
    for (int j = 0; j < 4; ++j) {
        unsigned lo = f2bf(src[(2 * j) * 3]);
        unsigned hi = f2bf(src[(2 * j + 1) * 3]);
        wrds[j] = lo | (hi << 16);
    }
    size_t dst = ((size_t)(nt * NKS + ks)) * (BN * BK) + nl * BK + 8 * (m ^ (nl & 7));
    *reinterpret_cast<uint4*>(Wp + dst) = make_uint4(wrds[0], wrds[1], wrds[2], wrds[3]);
}

// ---------------- kernel 2b: fp32 feat -> bf16 (covered rows only) ----------------
__global__ void cvt_kernel(const float* __restrict__ feat, const int* __restrict__ flags,
                           unsigned short* __restrict__ featbf) {
    int idx8 = blockIdx.x * 256 + threadIdx.x;   // 8 elems per thread
    if (idx8 >= NB * LLEN * DDIM / 8) return;
    int row = idx8 / (DDIM / 8);
    if (!(flags[row] & 1)) return;               // uncovered rows are never sourced
    const float* s = feat + (size_t)idx8 * 8;
    f32x4 a = *reinterpret_cast<const f32x4*>(s);
    f32x4 c = *reinterpret_cast<const f32x4*>(s + 4);
    ushort4 lo, hi;
    lo.x = f2bf(a.x); lo.y = f2bf(a.y); lo.z = f2bf(a.z); lo.w = f2bf(a.w);
    hi.x = f2bf(c.x); hi.y = f2bf(c.y); hi.z = f2bf(c.z); hi.w = f2bf(c.w);
    uint4 pack;
    pack.x = (unsigned)lo.x | ((unsigned)lo.y << 16);
    pack.y = (unsigned)lo.z | ((unsigned)lo.w << 16);
    pack.z = (unsigned)hi.x | ((unsigned)hi.y << 16);
    pack.w = (unsigned)hi.z | ((unsigned)hi.w << 16);
    *reinterpret_cast<uint4*>(featbf + (size_t)idx8 * 8) = pack;
}

// ---------------- kernel 3: R11 structure, 32x32x16 MFMA inner loop ----------------
// Same staging/swizzle/XCD mapping as R11 (82us verified). Only the compute and
// epilogue change: 32x32x16 runs the matrix pipe ~15% faster (2382 vs 2075 TF
// ubench) at HALF the MFMA instruction count; LDS read count/pattern unchanged
// (b128 reads stay uniform over 32 banks under the same XOR swizzle).
// A operand: lane holds row=l&31, k=(l>>5)*8..+8.  B: col=l&31, same k split.
// C/D (m74/m101 verified): col=lane&31, row=(reg&3)+8*(reg>>2)+4*(lane>>5).
__global__ __launch_bounds__(256, 4) void conv_mfma5_kernel(
    const unsigned short* __restrict__ featbf, const int* __restrict__ flags,
    const unsigned short* __restrict__ Wp, const float* __restrict__ bias,
    const unsigned short* __restrict__ zeropage, float* __restrict__ out)
{
    int s    = blockIdx.x;          // grid = 1536 = 8 XCD * 192 slots
    int xcd  = s & 7;
    int slot = s >> 3;              // [0,192)
    int b    = slot / NTILE;        // batch [0,32)
    int nt   = slot % NTILE;        // col tile [0,6)
    int pblk = (xcd - b) & 7;       // row-block within batch, rotated per batch
    int p0   = pblk * BM;
    int tid  = threadIdx.x;

    __shared__ int s_rf[BM];
    __shared__ int s_any;
    __shared__ float s_bias[BN];
    __shared__ __align__(16) unsigned char As[BM * BK * 2];   // 16 KB
    __shared__ __align__(16) unsigned char Bs[BK * BN * 2];   // 16 KB

    if (tid == 0) s_any = 0;
    __syncthreads();
    if (tid < BM) {
        int rf = flags[b * LLEN + p0 + tid];
        s_rf[tid] = rf;
        if (rf) atomicOr(&s_any, 1);
    }
    if (tid < BN) s_bias[tid] = bias[nt * BN + tid];
    __syncthreads();

    float* outbase = out + ((size_t)(b * LLEN + p0)) * DDIM + nt * BN;

    if (!s_any) {   // whole tile uncovered -> zeros
        f32x4 z = {0.f, 0.f, 0.f, 0.f};
        #pragma unroll
        for (int q = 0; q < 16; ++q) {
            int flat = q * 256 + tid;           // 128 rows x 32 float4
            int row = flat >> 5, c4 = flat & 31;
            *reinterpret_cast<f32x4*>(outbase + (size_t)row * DDIM + c4 * 4) = z;
        }
        return;
    }

    int w  = tid >> 6;
    int l  = tid & 63;
    int wr = w >> 1, wc = w & 1;     // 2x2 waves, each 64x64
    int l31 = l & 31, lh = l >> 5;   // 32-row lane index, k-half

    // per-thread A-staging descriptors (4 slots of 16B per k-step) -- unchanged
    int  useq[4];                      // bit t = tap t active for this slot's row
    const unsigned short* rowptr[4];   // featbf + row*768 + swizzled col chunk
    unsigned ldsoff[4];                // wave-uniform LDS 16B-slot base (bytes)
    #pragma unroll
    for (int q = 0; q < 4; ++q) {
        int flat = q * 256 + tid;
        int row = flat >> 3, c8 = flat & 7;
        int c8s = c8 ^ (row & 7);
        int rf = s_rf[row];
        useq[q] = ((rf >> 1) & 1) | ((rf & 1) << 1) | (((rf >> 2) & 1) << 2);
        rowptr[q] = featbf + ((size_t)(b * LLEN + p0 + row) * DDIM + c8s * 8);
        ldsoff[q] = (unsigned)(((q * 256) + (tid & 192)) * 16);
    }
    const unsigned short* WpBase = Wp + (size_t)nt * NKS * (BN * BK) + (size_t)tid * 8;

    auto stage = [&](int ks) {   // 8 loads total (4 A + 4 B), zero VGPR staging
        int tap = ks / (DDIM / BK);
        int i0  = (ks % (DDIM / BK)) * BK;
        #pragma unroll
        for (int q = 0; q < 4; ++q) {
            const unsigned short* src = ((useq[q] >> tap) & 1)
                ? rowptr[q] + (size_t)(tap - 1) * DDIM + i0
                : zeropage;
            gload_lds16(src, &As[ldsoff[q]]);
        }
        const unsigned short* bsrc = WpBase + (size_t)ks * (BN * BK);
        #pragma unroll
        for (int q = 0; q < 4; ++q)
            gload_lds16(bsrc + q * 256 * 8, &Bs[ldsoff[q]]);
    };

    f32x16 acc[2][2];
    #pragma unroll
    for (int i = 0; i < 2; ++i)
        #pragma unroll
        for (int j = 0; j < 2; ++j)
            #pragma unroll
            for (int r = 0; r < 16; ++r) acc[i][j][r] = 0.f;

    // fragment read offsets (byte) and swizzle masks, 32x32 layout
    unsigned abase[2], aswz[2], bbase[2], bswz[2];
    #pragma unroll
    for (int fm = 0; fm < 2; ++fm) {
        int row = wr * 64 + fm * 32 + l31;
        abase[fm] = (unsigned)(row * (BK * 2) + lh * 16);
        aswz[fm]  = ((unsigned)(row & 7) << 4);
    }
    #pragma unroll
    for (int fn = 0; fn < 2; ++fn) {
        int col = wc * 64 + fn * 32 + l31;
        bbase[fn] = (unsigned)(col * (BK * 2) + lh * 16);
        bswz[fn]  = ((unsigned)(col & 7) << 4);
    }

    auto compute = [&]() {
        #pragma unroll
        for (int ksub = 0; ksub < 4; ++ksub) {     // BK=64 = 4 x K16
            bf16x8 av[2], bv[2];
            #pragma unroll
            for (int fm = 0; fm < 2; ++fm)
                av[fm] = *reinterpret_cast<const bf16x8*>(As + ((abase[fm] + ksub * 32) ^ aswz[fm]));
            #pragma unroll
            for (int fn = 0; fn < 2; ++fn)
                bv[fn] = *reinterpret_cast<const bf16x8*>(Bs + ((bbase[fn] + ksub * 32) ^ bswz[fn]));
            #pragma unroll
            for (int fm = 0; fm < 2; ++fm)
                #pragma unroll
                for (int fn = 0; fn < 2; ++fn)
                    acc[fm][fn] = __builtin_amdgcn_mfma_f32_32x32x16_bf16(
                        av[fm], bv[fn], acc[fm][fn], 0, 0, 0);
        }
    };

    // m97-structure main loop; drain stall covered by 4 co-resident blocks.
    #pragma unroll 1
    for (int ks = 0; ks < NKS; ++ks) {
        stage(ks);
        __syncthreads();     // compiler emits vmcnt(0) drain: tile ready
        compute();
        __syncthreads();     // all waves done reading before overwrite
    }

    // ---- epilogue: bias + relu, invalid rows -> 0 (32x32 C/D layout) ----
    #pragma unroll
    for (int fm = 0; fm < 2; ++fm) {
        #pragma unroll
        for (int fn = 0; fn < 2; ++fn) {
            int colL = wc * 64 + fn * 32 + l31;
            float bn = s_bias[colL];
            #pragma unroll
            for (int r = 0; r < 16; ++r) {
                int rowL = wr * 64 + fm * 32 + (r & 3) + 8 * (r >> 2) + 4 * lh;
                int rf = s_rf[rowL];
                float v = (rf & 1) ? fmaxf(acc[fm][fn][r] + bn, 0.f) : 0.f;
                outbase[(size_t)rowL * DDIM + colL] = v;
            }
        }
    }
}

// ---------------- fallback kernel (fp32 in-loop conversion, small ws) ----------------
__global__ __launch_bounds__(256) void conv_mfma_kernel(
    const float* __restrict__ feat, const int* __restrict__ flags,
    const unsigned short* __restrict__ Wp, const float* __restrict__ bias,
    float* __restrict__ out)
{
    int nt = blockIdx.x % NTILE;
    int rb = blockIdx.x / NTILE;
    int b  = rb / (LLEN / BM);
    int p0 = (rb % (LLEN / BM)) * BM;
    int tid = threadIdx.x;

    __shared__ int s_rf[BM];
    __shared__ int s_any;
    __shared__ float s_bias[BN];
    __shared__ __align__(16) unsigned char As[BM * BK * 2];
    __shared__ __align__(16) unsigned char Bs[BK * BN * 2];

    if (tid == 0) s_any = 0;
    __syncthreads();
    if (tid < BM) {
        int rf = flags[b * LLEN + p0 + tid];
        s_rf[tid] = rf;
        if (rf) atomicOr(&s_any, 1);
    }
    if (tid < BN) s_bias[tid] = bias[nt * BN + tid];
    __syncthreads();

    float* outbase = out + ((size_t)(b * LLEN + p0)) * DDIM + nt * BN;

    if (!s_any) {
        f32x4 z = {0.f, 0.f, 0.f, 0.f};
        #pragma unroll
        for (int q = 0; q < 16; ++q) {
            int flat = q * 256 + tid;
            int row = flat >> 5, c4 = flat & 31;
            *reinterpret_cast<f32x4*>(outbase + (size_t)row * DDIM + c4 * 4) = z;
        }
        return;
    }

    int w  = tid >> 6;
    int l  = tid & 63;
    int wr = w >> 1, wc = w & 1;
    int lr = l & 15, lg = l >> 4;

    f32x4 acc[4][4];
    #pragma unroll
    for (int i = 0; i < 4; ++i)
        #pragma unroll
        for (int j = 0; j < 4; ++j) acc[i][j] = (f32x4){0.f, 0.f, 0.f, 0.f};

    unsigned abase[4], aswz[4], bbase[4], bswz[4];
    #pragma unroll
    for (int fm = 0; fm < 4; ++fm) {
        int row = wr * 64 + fm * 16 + lr;
        abase[fm] = (unsigned)(row * (BK * 2) + lg * 16);
        aswz[fm]  = ((unsigned)(row & 7) << 4);
    }
    #pragma unroll
    for (int fn = 0; fn < 4; ++fn) {
        int col = wc * 64 + fn * 16 + lr;
        bbase[fn] = (unsigned)(col * (BK * 2) + lg * 16);
        bswz[fn]  = ((unsigned)(col & 7) << 4);
    }

    const unsigned short* WpBase = Wp + (size_t)nt * NKS * (BN * BK);

    for (int ks = 0; ks < NKS; ++ks) {
        int tap = ks / (DDIM / BK);
        int i0  = (ks % (DDIM / BK)) * BK;

        #pragma unroll
        for (int q = 0; q < 8; ++q) {
            int flat = q * 256 + tid;
            int row = flat >> 4, c4 = flat & 15;
            int rf = s_rf[row];
            int use = (tap == 0) ? ((rf >> 1) & 1) : (tap == 1) ? (rf & 1) : ((rf >> 2) & 1);
            unsigned lo = 0, hi = 0;
            if (use) {
                int p = p0 + row + tap - 1;
                const float* src = feat + ((size_t)(b * LLEN + p)) * DDIM + i0 + c4 * 4;
                f32x4 v = *reinterpret_cast<const f32x4*>(src);
                lo = (unsigned)f2bf(v.x) | ((unsigned)f2bf(v.y) << 16);
                hi = (unsigned)f2bf(v.z) | ((unsigned)f2bf(v.w) << 16);
            }
            unsigned byte = (unsigned)(row * (BK * 2) + c4 * 8);
            byte ^= ((unsigned)(row & 7) << 4);
            *reinterpret_cast<uint2*>(As + byte) = make_uint2(lo, hi);
        }

        {
            const uint4* src = reinterpret_cast<const uint4*>(WpBase + (size_t)ks * (BN * BK));
            uint4* dst = reinterpret_cast<uint4*>(Bs);
            #pragma unroll
            for (int q = 0; q < 4; ++q) {
                int f16 = q * 256 + tid;
                dst[f16] = src[f16];
            }
        }
        __syncthreads();

        #pragma unroll
        for (int kc = 0; kc < 2; ++kc) {
            bf16x8 av[4], bv[4];
            #pragma unroll
            for (int fm = 0; fm < 4; ++fm)
                av[fm] = *reinterpret_cast<const bf16x8*>(As + ((abase[fm] + kc * 64) ^ aswz[fm]));
            #pragma unroll
            for (int fn = 0; fn < 4; ++fn)
                bv[fn] = *reinterpret_cast<const bf16x8*>(Bs + ((bbase[fn] + kc * 64) ^ bswz[fn]));
            #pragma unroll
            for (int fm = 0; fm < 4; ++fm)
                #pragma unroll
                for (int fn = 0; fn < 4; ++fn)
                    acc[fm][fn] = __builtin_amdgcn_mfma_f32_16x16x32_bf16(
                        av[fm], bv[fn], acc[fm][fn], 0, 0, 0);
        }
        __syncthreads();
    }

    #pragma unroll
    for (int fm = 0; fm < 4; ++fm) {
        #pragma unroll
        for (int fn = 0; fn < 4; ++fn) {
            int colL = wc * 64 + fn * 16 + lr;
            float bn = s_bias[colL];
            #pragma unroll
            for (int j = 0; j < 4; ++j) {
                int rowL = wr * 64 + fm * 16 + lg * 4 + j;
                int rf = s_rf[rowL];
                float v = (rf & 1) ? fmaxf(acc[fm][fn][j] + bn, 0.f) : 0.f;
                outbase[(size_t)rowL * DDIM + colL] = v;
            }
        }
    }
}

extern "C" void kernel_launch(void* const* d_in, const int* in_sizes, int n_in,
                              void* d_out, int out_size, void* d_ws, size_t ws_size,
                              hipStream_t stream) {
    const float* feat = (const float*)d_in[0];        // [B,L,D] fp32
    const int*   lens = (const int*)d_in[1];          // [B,C] int32
    const float* cw   = (const float*)d_in[2];        // [D,D,3] fp32
    const float* cb   = (const float*)d_in[3];        // [D] fp32
    float* outp = (float*)d_out;

    char* ws = (char*)d_ws;
    int* flags = (int*)(ws + FLAGS_OFF);
    unsigned short* Wp = (unsigned short*)(ws + WP_OFF);
    unsigned int* zeropage = (unsigned int*)(ws + ZP_OFF);

    meta_kernel<<<NB, CCH, 0, stream>>>(lens, flags);
    packw2_kernel<<<(NTILE * NKS * BN * 8 + 255) / 256 + 1, 256, 0, stream>>>(cw, Wp, zeropage);

    if (ws_size >= WS_NEED) {
        unsigned short* featbf = (unsigned short*)(ws + FB_OFF);
        cvt_kernel<<<(NB * LLEN * DDIM / 8 + 255) / 256, 256, 0, stream>>>(feat, flags, featbf);
        conv_mfma5_kernel<<<NRB * NTILE, 256, 0, stream>>>(featbf, flags, Wp, cb,
                                                           (const unsigned short*)zeropage, outp);
    } else {
        conv_mfma_kernel<<<NRB * NTILE, 256, 0, stream>>>(feat, flags, Wp, cb, outp);
    }
}

// Round 13
// 105.650 us; speedup vs baseline: 1.0301x; 1.0301x over previous
//
#include <hip/hip_runtime.h>
#include <stdint.h>

// Problem constants
constexpr int NB   = 32;     // batch
constexpr int LLEN = 1024;   // max wordpiece len
constexpr int DDIM = 768;    // hidden
constexpr int CCH  = 256;    // max chunks
constexpr int KMAX = 8;      // max chunk len
constexpr int KTOT = 3 * DDIM;   // 2304 reduction dim (3 taps x D)

// GEMM tiling
constexpr int BM = 128;
constexpr int BN = 128;
constexpr int BK = 64;
constexpr int NKS = KTOT / BK;       // 36 k-steps
constexpr int NTILE = DDIM / BN;     // 6 col tiles
constexpr int NRB = NB * LLEN / BM;  // 256 row blocks

// ws layout (bytes)
constexpr size_t FLAGS_OFF = 0;
constexpr size_t FLAGS_SZ  = (size_t)NB * LLEN * sizeof(int);           // 128 KB
constexpr size_t WP_OFF    = FLAGS_OFF + FLAGS_SZ;
constexpr size_t WP_SZ     = (size_t)NTILE * NKS * BN * BK * 2;         // 3.456 MB
constexpr size_t ZP_OFF    = WP_OFF + WP_SZ;
constexpr size_t ZP_SZ     = 256;
constexpr size_t FB_OFF    = ZP_OFF + ZP_SZ;
constexpr size_t FB_SZ     = (size_t)NB * LLEN * DDIM * 2;              // 50.33 MB
constexpr size_t WS_NEED   = FB_OFF + FB_SZ;

typedef __attribute__((ext_vector_type(4))) float f32x4;
typedef __bf16 bf16x8 __attribute__((ext_vector_type(8)));

__device__ inline unsigned short f2bf(float f) {
    unsigned u = __float_as_uint(f);
    u = u + 0x7FFFu + ((u >> 16) & 1u);   // round-to-nearest-even
    return (unsigned short)(u >> 16);
}

__device__ inline void gload_lds16(const void* g, void* l) {
    __builtin_amdgcn_global_load_lds(
        (const __attribute__((address_space(1))) unsigned int*)g,
        (__attribute__((address_space(3))) unsigned int*)l, 16, 0, 0);
}

// ---------------- kernel 1: per-row flags from chunk_lens ----------------
// flags[b*L + p] : bit0 = valid, bit1 = has_left (k>0), bit2 = has_right (k+1<trunc)
__global__ void meta_kernel(const int* __restrict__ chunk_lens, int* __restrict__ flags) {
    int b = blockIdx.x, tid = threadIdx.x;   // blockDim = 256 == CCH
    __shared__ int s[CCH];
    int len = chunk_lens[b * CCH + tid];
    s[tid] = len;
    __syncthreads();
    for (int off = 1; off < CCH; off <<= 1) {
        int v = (tid >= off) ? s[tid - off] : 0;
        __syncthreads();
        s[tid] += v;
        __syncthreads();
    }
    int start = s[tid] - len;   // exclusive cumsum
    for (int i = tid; i < LLEN; i += CCH) flags[b * LLEN + i] = 0;
    __syncthreads();
    int t = min(len, KMAX);
    for (int k = 0; k < t; ++k) {
        int p = start + k;
        if (p < LLEN)
            flags[b * LLEN + p] = 1 | (k > 0 ? 2 : 0) | (k + 1 < t ? 4 : 0);
    }
}

// ---------------- kernel 2: pack conv_w -> bf16 swizzled B images (vectorized) ----
// R9/R11-verified. One thread emits 8 contiguous swizzled elements (the XOR
// permutes 8-element granules) = one dwordx4 store. Last block zeroes the zeropage.
__global__ void packw2_kernel(const float* __restrict__ conv_w, unsigned short* __restrict__ Wp,
                              unsigned int* __restrict__ zeropage) {
    if (blockIdx.x == gridDim.x - 1) {
        if (threadIdx.x < (int)(ZP_SZ / 4)) zeropage[threadIdx.x] = 0u;
        return;
    }
    int idx = blockIdx.x * 256 + threadIdx.x;   // [0, 6*36*128*8 = 221184)
    if (idx >= NTILE * NKS * BN * 8) return;
    int m    = idx & 7;
    int nl   = (idx >> 3) & (BN - 1);
    int rest = idx >> 10;             // nt*NKS + ks in [0,216)
    int ks   = rest % NKS;
    int nt   = rest / NKS;
    int n    = nt * BN + nl;
    int k0   = ks * BK + m * 8;       // 8-run never crosses a tap boundary (768%64==0)
    int tap  = k0 / DDIM;
    int i0   = k0 % DDIM;
    const float* src = conv_w + ((size_t)n * DDIM + i0) * 3 + tap;  // stride-3 gather
    unsigned wrds[4];
    #pragma unroll
    for (int j = 0; j < 4; ++j) {
        unsigned lo = f2bf(src[(2 * j) * 3]);
        unsigned hi = f2bf(src[(2 * j + 1) * 3]);
        wrds[j] = lo | (hi << 16);
    }
    size_t dst = ((size_t)(nt * NKS + ks)) * (BN * BK) + nl * BK + 8 * (m ^ (nl & 7));
    *reinterpret_cast<uint4*>(Wp + dst) = make_uint4(wrds[0], wrds[1], wrds[2], wrds[3]);
}

// ---------------- kernel 2b: fp32 feat -> bf16 (covered rows only) ----------------
__global__ void cvt_kernel(const float* __restrict__ feat, const int* __restrict__ flags,
                           unsigned short* __restrict__ featbf) {
    int idx8 = blockIdx.x * 256 + threadIdx.x;   // 8 elems per thread
    if (idx8 >= NB * LLEN * DDIM / 8) return;
    int row = idx8 / (DDIM / 8);
    if (!(flags[row] & 1)) return;               // uncovered rows are never sourced
    const float* s = feat + (size_t)idx8 * 8;
    f32x4 a = *reinterpret_cast<const f32x4*>(s);
    f32x4 c = *reinterpret_cast<const f32x4*>(s + 4);
    ushort4 lo, hi;
    lo.x = f2bf(a.x); lo.y = f2bf(a.y); lo.z = f2bf(a.z); lo.w = f2bf(a.w);
    hi.x = f2bf(c.x); hi.y = f2bf(c.y); hi.z = f2bf(c.z); hi.w = f2bf(c.w);
    uint4 pack;
    pack.x = (unsigned)lo.x | ((unsigned)lo.y << 16);
    pack.y = (unsigned)lo.z | ((unsigned)lo.w << 16);
    pack.z = (unsigned)hi.x | ((unsigned)hi.y << 16);
    pack.w = (unsigned)hi.z | ((unsigned)hi.w << 16);
    *reinterpret_cast<uint4*>(featbf + (size_t)idx8 * 8) = pack;
}

// ---------------- kernel 3: R11 GEMM (16x16 MFMA, conflict-free) + T5 setprio ----
// R12 lesson: 32x32 fragment reads conflict under this swizzle (7.85M conflicts,
// -13%). Reverted to the 16x16 pattern (0 conflicts, 82us verified). Single new
// lever vs R11: s_setprio(1) around the MFMA cluster — with 4 independent
// blocks/CU at different phases, favor MFMA-issuing waves (T5, m191 mechanism).
__global__ __launch_bounds__(256, 4) void conv_mfma6_kernel(
    const unsigned short* __restrict__ featbf, const int* __restrict__ flags,
    const unsigned short* __restrict__ Wp, const float* __restrict__ bias,
    const unsigned short* __restrict__ zeropage, float* __restrict__ out)
{
    int s    = blockIdx.x;          // grid = 1536 = 8 XCD * 192 slots
    int xcd  = s & 7;
    int slot = s >> 3;              // [0,192)
    int b    = slot / NTILE;        // batch [0,32)
    int nt   = slot % NTILE;        // col tile [0,6)
    int pblk = (xcd - b) & 7;       // row-block within batch, rotated per batch
    int p0   = pblk * BM;
    int tid  = threadIdx.x;

    __shared__ int s_rf[BM];
    __shared__ int s_any;
    __shared__ float s_bias[BN];
    __shared__ __align__(16) unsigned char As[BM * BK * 2];   // 16 KB
    __shared__ __align__(16) unsigned char Bs[BK * BN * 2];   // 16 KB

    if (tid == 0) s_any = 0;
    __syncthreads();
    if (tid < BM) {
        int rf = flags[b * LLEN + p0 + tid];
        s_rf[tid] = rf;
        if (rf) atomicOr(&s_any, 1);
    }
    if (tid < BN) s_bias[tid] = bias[nt * BN + tid];
    __syncthreads();

    float* outbase = out + ((size_t)(b * LLEN + p0)) * DDIM + nt * BN;

    if (!s_any) {   // whole tile uncovered -> zeros
        f32x4 z = {0.f, 0.f, 0.f, 0.f};
        #pragma unroll
        for (int q = 0; q < 16; ++q) {
            int flat = q * 256 + tid;           // 128 rows x 32 float4
            int row = flat >> 5, c4 = flat & 31;
            *reinterpret_cast<f32x4*>(outbase + (size_t)row * DDIM + c4 * 4) = z;
        }
        return;
    }

    int w  = tid >> 6;
    int l  = tid & 63;
    int wr = w >> 1, wc = w & 1;     // 2x2 waves, each 64x64
    int lr = l & 15, lg = l >> 4;

    // per-thread A-staging descriptors (4 slots of 16B per k-step)
    int  useq[4];                      // bit t = tap t active for this slot's row
    const unsigned short* rowptr[4];   // featbf + row*768 + swizzled col chunk
    unsigned ldsoff[4];                // wave-uniform LDS 16B-slot base (bytes)
    #pragma unroll
    for (int q = 0; q < 4; ++q) {
        int flat = q * 256 + tid;
        int row = flat >> 3, c8 = flat & 7;
        int c8s = c8 ^ (row & 7);
        int rf = s_rf[row];
        useq[q] = ((rf >> 1) & 1) | ((rf & 1) << 1) | (((rf >> 2) & 1) << 2);
        rowptr[q] = featbf + ((size_t)(b * LLEN + p0 + row) * DDIM + c8s * 8);
        ldsoff[q] = (unsigned)(((q * 256) + (tid & 192)) * 16);
    }
    const unsigned short* WpBase = Wp + (size_t)nt * NKS * (BN * BK) + (size_t)tid * 8;

    auto stage = [&](int ks) {   // 8 loads total (4 A + 4 B), zero VGPR staging
        int tap = ks / (DDIM / BK);
        int i0  = (ks % (DDIM / BK)) * BK;
        #pragma unroll
        for (int q = 0; q < 4; ++q) {
            const unsigned short* src = ((useq[q] >> tap) & 1)
                ? rowptr[q] + (size_t)(tap - 1) * DDIM + i0
                : zeropage;
            gload_lds16(src, &As[ldsoff[q]]);
        }
        const unsigned short* bsrc = WpBase + (size_t)ks * (BN * BK);
        #pragma unroll
        for (int q = 0; q < 4; ++q)
            gload_lds16(bsrc + q * 256 * 8, &Bs[ldsoff[q]]);
    };

    f32x4 acc[4][4];
    #pragma unroll
    for (int i = 0; i < 4; ++i)
        #pragma unroll
        for (int j = 0; j < 4; ++j) acc[i][j] = (f32x4){0.f, 0.f, 0.f, 0.f};

    unsigned abase[4], aswz[4], bbase[4], bswz[4];
    #pragma unroll
    for (int fm = 0; fm < 4; ++fm) {
        int row = wr * 64 + fm * 16 + lr;
        abase[fm] = (unsigned)(row * (BK * 2) + lg * 16);
        aswz[fm]  = ((unsigned)(row & 7) << 4);
    }
    #pragma unroll
    for (int fn = 0; fn < 4; ++fn) {
        int col = wc * 64 + fn * 16 + lr;
        bbase[fn] = (unsigned)(col * (BK * 2) + lg * 16);
        bswz[fn]  = ((unsigned)(col & 7) << 4);
    }

    auto compute = [&]() {
        #pragma unroll
        for (int kc = 0; kc < 2; ++kc) {
            bf16x8 av[4], bv[4];
            #pragma unroll
            for (int fm = 0; fm < 4; ++fm)
                av[fm] = *reinterpret_cast<const bf16x8*>(As + ((abase[fm] + kc * 64) ^ aswz[fm]));
            #pragma unroll
            for (int fn = 0; fn < 4; ++fn)
                bv[fn] = *reinterpret_cast<const bf16x8*>(Bs + ((bbase[fn] + kc * 64) ^ bswz[fn]));
            __builtin_amdgcn_s_setprio(1);           // T5: favor MFMA-issuing waves
            #pragma unroll
            for (int fm = 0; fm < 4; ++fm)
                #pragma unroll
                for (int fn = 0; fn < 4; ++fn)
                    acc[fm][fn] = __builtin_amdgcn_mfma_f32_16x16x32_bf16(
                        av[fm], bv[fn], acc[fm][fn], 0, 0, 0);
            __builtin_amdgcn_s_setprio(0);
        }
    };

    // m97-structure main loop; drain stall covered by 4 co-resident blocks.
    #pragma unroll 1
    for (int ks = 0; ks < NKS; ++ks) {
        stage(ks);
        __syncthreads();     // compiler emits vmcnt(0) drain: tile ready
        compute();
        __syncthreads();     // all waves done reading before overwrite
    }

    // ---- epilogue: bias + relu, invalid rows -> 0 ----
    #pragma unroll
    for (int fm = 0; fm < 4; ++fm) {
        #pragma unroll
        for (int fn = 0; fn < 4; ++fn) {
            int colL = wc * 64 + fn * 16 + lr;
            float bn = s_bias[colL];
            #pragma unroll
            for (int j = 0; j < 4; ++j) {
                int rowL = wr * 64 + fm * 16 + lg * 4 + j;
                int rf = s_rf[rowL];
                float v = (rf & 1) ? fmaxf(acc[fm][fn][j] + bn, 0.f) : 0.f;
                outbase[(size_t)rowL * DDIM + colL] = v;
            }
        }
    }
}

// ---------------- fallback kernel (fp32 in-loop conversion, small ws) ----------------
__global__ __launch_bounds__(256) void conv_mfma_kernel(
    const float* __restrict__ feat, const int* __restrict__ flags,
    const unsigned short* __restrict__ Wp, const float* __restrict__ bias,
    float* __restrict__ out)
{
    int nt = blockIdx.x % NTILE;
    int rb = blockIdx.x / NTILE;
    int b  = rb / (LLEN / BM);
    int p0 = (rb % (LLEN / BM)) * BM;
    int tid = threadIdx.x;

    __shared__ int s_rf[BM];
    __shared__ int s_any;
    __shared__ float s_bias[BN];
    __shared__ __align__(16) unsigned char As[BM * BK * 2];
    __shared__ __align__(16) unsigned char Bs[BK * BN * 2];

    if (tid == 0) s_any = 0;
    __syncthreads();
    if (tid < BM) {
        int rf = flags[b * LLEN + p0 + tid];
        s_rf[tid] = rf;
        if (rf) atomicOr(&s_any, 1);
    }
    if (tid < BN) s_bias[tid] = bias[nt * BN + tid];
    __syncthreads();

    float* outbase = out + ((size_t)(b * LLEN + p0)) * DDIM + nt * BN;

    if (!s_any) {
        f32x4 z = {0.f, 0.f, 0.f, 0.f};
        #pragma unroll
        for (int q = 0; q < 16; ++q) {
            int flat = q * 256 + tid;
            int row = flat >> 5, c4 = flat & 31;
            *reinterpret_cast<f32x4*>(outbase + (size_t)row * DDIM + c4 * 4) = z;
        }
        return;
    }

    int w  = tid >> 6;
    int l  = tid & 63;
    int wr = w >> 1, wc = w & 1;
    int lr = l & 15, lg = l >> 4;

    f32x4 acc[4][4];
    #pragma unroll
    for (int i = 0; i < 4; ++i)
        #pragma unroll
        for (int j = 0; j < 4; ++j) acc[i][j] = (f32x4){0.f, 0.f, 0.f, 0.f};

    unsigned abase[4], aswz[4], bbase[4], bswz[4];
    #pragma unroll
    for (int fm = 0; fm < 4; ++fm) {
        int row = wr * 64 + fm * 16 + lr;
        abase[fm] = (unsigned)(row * (BK * 2) + lg * 16);
        aswz[fm]  = ((unsigned)(row & 7) << 4);
    }
    #pragma unroll
    for (int fn = 0; fn < 4; ++fn) {
        int col = wc * 64 + fn * 16 + lr;
        bbase[fn] = (unsigned)(col * (BK * 2) + lg * 16);
        bswz[fn]  = ((unsigned)(col & 7) << 4);
    }

    const unsigned short* WpBase = Wp + (size_t)nt * NKS * (BN * BK);

    for (int ks = 0; ks < NKS; ++ks) {
        int tap = ks / (DDIM / BK);
        int i0  = (ks % (DDIM / BK)) * BK;

        #pragma unroll
        for (int q = 0; q < 8; ++q) {
            int flat = q * 256 + tid;
            int row = flat >> 4, c4 = flat & 15;
            int rf = s_rf[row];
            int use = (tap == 0) ? ((rf >> 1) & 1) : (tap == 1) ? (rf & 1) : ((rf >> 2) & 1);
            unsigned lo = 0, hi = 0;
            if (use) {
                int p = p0 + row + tap - 1;
                const float* src = feat + ((size_t)(b * LLEN + p)) * DDIM + i0 + c4 * 4;
                f32x4 v = *reinterpret_cast<const f32x4*>(src);
                lo = (unsigned)f2bf(v.x) | ((unsigned)f2bf(v.y) << 16);
                hi = (unsigned)f2bf(v.z) | ((unsigned)f2bf(v.w) << 16);
            }
            unsigned byte = (unsigned)(row * (BK * 2) + c4 * 8);
            byte ^= ((unsigned)(row & 7) << 4);
            *reinterpret_cast<uint2*>(As + byte) = make_uint2(lo, hi);
        }

        {
            const uint4* src = reinterpret_cast<const uint4*>(WpBase + (size_t)ks * (BN * BK));
            uint4* dst = reinterpret_cast<uint4*>(Bs);
            #pragma unroll
            for (int q = 0; q < 4; ++q) {
                int f16 = q * 256 + tid;
                dst[f16] = src[f16];
            }
        }
        __syncthreads();

        #pragma unroll
        for (int kc = 0; kc < 2; ++kc) {
            bf16x8 av[4], bv[4];
            #pragma unroll
            for (int fm = 0; fm < 4; ++fm)
                av[fm] = *reinterpret_cast<const bf16x8*>(As + ((abase[fm] + kc * 64) ^ aswz[fm]));
            #pragma unroll
            for (int fn = 0; fn < 4; ++fn)
                bv[fn] = *reinterpret_cast<const bf16x8*>(Bs + ((bbase[fn] + kc * 64) ^ bswz[fn]));
            #pragma unroll
            for (int fm = 0; fm < 4; ++fm)
                #pragma unroll
                for (int fn = 0; fn < 4; ++fn)
                    acc[fm][fn] = __builtin_amdgcn_mfma_f32_16x16x32_bf16(
                        av[fm], bv[fn], acc[fm][fn], 0, 0, 0);
        }
        __syncthreads();
    }

    #pragma unroll
    for (int fm = 0; fm < 4; ++fm) {
        #pragma unroll
        for (int fn = 0; fn < 4; ++fn) {
            int colL = wc * 64 + fn * 16 + lr;
            float bn = s_bias[colL];
            #pragma unroll
            for (int j = 0; j < 4; ++j) {
                int rowL = wr * 64 + fm * 16 + lg * 4 + j;
                int rf = s_rf[rowL];
                float v = (rf & 1) ? fmaxf(acc[fm][fn][j] + bn, 0.f) : 0.f;
                outbase[(size_t)rowL * DDIM + colL] = v;
            }
        }
    }
}

extern "C" void kernel_launch(void* const* d_in, const int* in_sizes, int n_in,
                              void* d_out, int out_size, void* d_ws, size_t ws_size,
                              hipStream_t stream) {
    const float* feat = (const float*)d_in[0];        // [B,L,D] fp32
    const int*   lens = (const int*)d_in[1];          // [B,C] int32
    const float* cw   = (const float*)d_in[2];        // [D,D,3] fp32
    const float* cb   = (const float*)d_in[3];        // [D] fp32
    float* outp = (float*)d_out;

    char* ws = (char*)d_ws;
    int* flags = (int*)(ws + FLAGS_OFF);
    unsigned short* Wp = (unsigned short*)(ws + WP_OFF);
    unsigned int* zeropage = (unsigned int*)(ws + ZP_OFF);

    meta_kernel<<<NB, CCH, 0, stream>>>(lens, flags);
    packw2_kernel<<<(NTILE * NKS * BN * 8 + 255) / 256 + 1, 256, 0, stream>>>(cw, Wp, zeropage);

    if (ws_size >= WS_NEED) {
        unsigned short* featbf = (unsigned short*)(ws + FB_OFF);
        cvt_kernel<<<(NB * LLEN * DDIM / 8 + 255) / 256, 256, 0, stream>>>(feat, flags, featbf);
        conv_mfma6_kernel<<<NRB * NTILE, 256, 0, stream>>>(featbf, flags, Wp, cb,
                                                           (const unsigned short*)zeropage, outp);
    } else {
        conv_mfma_kernel<<<NRB * NTILE, 256, 0, stream>>>(feat, flags, Wp, cb, outp);
    }
}

// Round 14
// 97.218 us; speedup vs baseline: 1.1195x; 1.0867x over previous
//
#include <hip/hip_runtime.h>
#include <stdint.h>

// Problem constants
constexpr int NB   = 32;     // batch
constexpr int LLEN = 1024;   // max wordpiece len
constexpr int DDIM = 768;    // hidden
constexpr int CCH  = 256;    // max chunks
constexpr int KMAX = 8;      // max chunk len
constexpr int KTOT = 3 * DDIM;   // 2304 reduction dim (3 taps x D)

// GEMM tiling
constexpr int BM = 128;
constexpr int BN = 128;
constexpr int BK = 64;
constexpr int NKS = KTOT / BK;       // 36 k-steps
constexpr int NTILE = DDIM / BN;     // 6 col tiles
constexpr int NRB = NB * LLEN / BM;  // 256 row blocks

// fused meta+cvt
constexpr int CVT_SLICES = 32;                    // blocks per batch
constexpr int ROWS_PER_SLICE = LLEN / CVT_SLICES; // 32

// ws layout (bytes)
constexpr size_t FLAGS_OFF = 0;
constexpr size_t FLAGS_SZ  = (size_t)NB * LLEN * sizeof(int);           // 128 KB
constexpr size_t WP_OFF    = FLAGS_OFF + FLAGS_SZ;
constexpr size_t WP_SZ     = (size_t)NTILE * NKS * BN * BK * 2;         // 3.456 MB
constexpr size_t ZP_OFF    = WP_OFF + WP_SZ;
constexpr size_t ZP_SZ     = 256;
constexpr size_t FB_OFF    = ZP_OFF + ZP_SZ;
constexpr size_t FB_SZ     = (size_t)NB * LLEN * DDIM * 2;              // 50.33 MB
constexpr size_t WS_NEED   = FB_OFF + FB_SZ;

typedef __attribute__((ext_vector_type(4))) float f32x4;
typedef __bf16 bf16x8 __attribute__((ext_vector_type(8)));

__device__ inline unsigned short f2bf(float f) {
    unsigned u = __float_as_uint(f);
    u = u + 0x7FFFu + ((u >> 16) & 1u);   // round-to-nearest-even
    return (unsigned short)(u >> 16);
}

__device__ inline void gload_lds16(const void* g, void* l) {
    __builtin_amdgcn_global_load_lds(
        (const __attribute__((address_space(1))) unsigned int*)g,
        (__attribute__((address_space(3))) unsigned int*)l, 16, 0, 0);
}

// ---------------- kernel 1 (fallback path only): per-row flags ----------------
__global__ void meta_kernel(const int* __restrict__ chunk_lens, int* __restrict__ flags) {
    int b = blockIdx.x, tid = threadIdx.x;   // blockDim = 256 == CCH
    __shared__ int s[CCH];
    int len = chunk_lens[b * CCH + tid];
    s[tid] = len;
    __syncthreads();
    for (int off = 1; off < CCH; off <<= 1) {
        int v = (tid >= off) ? s[tid - off] : 0;
        __syncthreads();
        s[tid] += v;
        __syncthreads();
    }
    int start = s[tid] - len;   // exclusive cumsum
    for (int i = tid; i < LLEN; i += CCH) flags[b * LLEN + i] = 0;
    __syncthreads();
    int t = min(len, KMAX);
    for (int k = 0; k < t; ++k) {
        int p = start + k;
        if (p < LLEN)
            flags[b * LLEN + p] = 1 | (k > 0 ? 2 : 0) | (k + 1 < t ? 4 : 0);
    }
}

// ---------------- kernel 1b (fast path): FUSED meta + cvt ----------------
// 32 blocks per batch. Each redoes the cheap 256-len scan (few hundred cycles,
// amortized across blocks) and builds the batch's full flag image in LDS
// (chunk scatter targets are disjoint: starts are an exclusive cumsum).
// Slice-0 blocks persist flags for the GEMM; every block converts its
// 32-row slice fp32->bf16 using LDS flags. Removes one launch + the
// flags global round-trip between meta and cvt.
__global__ void meta_cvt_kernel(const int* __restrict__ chunk_lens,
                                const float* __restrict__ feat,
                                int* __restrict__ flags,
                                unsigned short* __restrict__ featbf) {
    int blk = blockIdx.x;              // [0, NB*CVT_SLICES)
    int b   = blk / CVT_SLICES;
    int sl  = blk % CVT_SLICES;
    int tid = threadIdx.x;             // 256

    __shared__ int s[CCH];
    __shared__ int fl[LLEN];           // 4 KB

    int len = chunk_lens[b * CCH + tid];
    s[tid] = len;
    for (int i = tid; i < LLEN; i += 256) fl[i] = 0;
    __syncthreads();
    for (int off = 1; off < CCH; off <<= 1) {
        int v = (tid >= off) ? s[tid - off] : 0;
        __syncthreads();
        s[tid] += v;
        __syncthreads();
    }
    int start = s[tid] - len;          // exclusive cumsum
    int t = min(len, KMAX);
    for (int k = 0; k < t; ++k) {      // disjoint targets -> non-atomic OK
        int p = start + k;
        if (p < LLEN)
            fl[p] = 1 | (k > 0 ? 2 : 0) | (k + 1 < t ? 4 : 0);
    }
    __syncthreads();

    if (sl == 0) {                     // persist flags for the GEMM kernel
        for (int i = tid; i < LLEN; i += 256)
            flags[b * LLEN + i] = fl[i];
    }

    // convert rows [sl*32, sl*32+32), covered rows only
    constexpr int CH = DDIM / 8;       // 96 8-elem chunks per row
    int r0 = sl * ROWS_PER_SLICE;
    for (int i = tid; i < ROWS_PER_SLICE * CH; i += 256) {
        int row = r0 + i / CH;
        if (!(fl[row] & 1)) continue;
        int c = i % CH;
        size_t base = ((size_t)(b * LLEN + row)) * DDIM + c * 8;
        f32x4 a  = *reinterpret_cast<const f32x4*>(feat + base);
        f32x4 cc = *reinterpret_cast<const f32x4*>(feat + base + 4);
        uint4 pack;
        pack.x = (unsigned)f2bf(a.x)  | ((unsigned)f2bf(a.y)  << 16);
        pack.y = (unsigned)f2bf(a.z)  | ((unsigned)f2bf(a.w)  << 16);
        pack.z = (unsigned)f2bf(cc.x) | ((unsigned)f2bf(cc.y) << 16);
        pack.w = (unsigned)f2bf(cc.z) | ((unsigned)f2bf(cc.w) << 16);
        *reinterpret_cast<uint4*>(featbf + base) = pack;
    }
}

// ---------------- kernel 2: pack conv_w -> bf16 swizzled B images (vectorized) ----
// R9/R11-verified. One thread emits 8 contiguous swizzled elements (the XOR
// permutes 8-element granules) = one dwordx4 store. Last block zeroes the zeropage.
__global__ void packw2_kernel(const float* __restrict__ conv_w, unsigned short* __restrict__ Wp,
                              unsigned int* __restrict__ zeropage) {
    if (blockIdx.x == gridDim.x - 1) {
        if (threadIdx.x < (int)(ZP_SZ / 4)) zeropage[threadIdx.x] = 0u;
        return;
    }
    int idx = blockIdx.x * 256 + threadIdx.x;   // [0, 6*36*128*8 = 221184)
    if (idx >= NTILE * NKS * BN * 8) return;
    int m    = idx & 7;
    int nl   = (idx >> 3) & (BN - 1);
    int rest = idx >> 10;             // nt*NKS + ks in [0,216)
    int ks   = rest % NKS;
    int nt   = rest / NKS;
    int n    = nt * BN + nl;
    int k0   = ks * BK + m * 8;       // 8-run never crosses a tap boundary (768%64==0)
    int tap  = k0 / DDIM;
    int i0   = k0 % DDIM;
    const float* src = conv_w + ((size_t)n * DDIM + i0) * 3 + tap;  // stride-3 gather
    unsigned wrds[4];
    #pragma unroll
    for (int j = 0; j < 4; ++j) {
        unsigned lo = f2bf(src[(2 * j) * 3]);
        unsigned hi = f2bf(src[(2 * j + 1) * 3]);
        wrds[j] = lo | (hi << 16);
    }
    size_t dst = ((size_t)(nt * NKS + ks)) * (BN * BK) + nl * BK + 8 * (m ^ (nl & 7));
    *reinterpret_cast<uint4*>(Wp + dst) = make_uint4(wrds[0], wrds[1], wrds[2], wrds[3]);
}

// ---------------- kernel 3: R11 GEMM exactly (16x16 MFMA, no setprio) ----------
// R13 lesson: setprio(1) around the MFMA cluster HURT (-13%, MfmaUtil 32->28):
// T5 is null-to-negative on this lockstep barrier structure (m190). Reverted.
__global__ __launch_bounds__(256, 4) void conv_mfma3_kernel(
    const unsigned short* __restrict__ featbf, const int* __restrict__ flags,
    const unsigned short* __restrict__ Wp, const float* __restrict__ bias,
    const unsigned short* __restrict__ zeropage, float* __restrict__ out)
{
    int s    = blockIdx.x;          // grid = 1536 = 8 XCD * 192 slots
    int xcd  = s & 7;
    int slot = s >> 3;              // [0,192)
    int b    = slot / NTILE;        // batch [0,32)
    int nt   = slot % NTILE;        // col tile [0,6)
    int pblk = (xcd - b) & 7;       // row-block within batch, rotated per batch
    int p0   = pblk * BM;
    int tid  = threadIdx.x;

    __shared__ int s_rf[BM];
    __shared__ int s_any;
    __shared__ float s_bias[BN];
    __shared__ __align__(16) unsigned char As[BM * BK * 2];   // 16 KB
    __shared__ __align__(16) unsigned char Bs[BK * BN * 2];   // 16 KB

    if (tid == 0) s_any = 0;
    __syncthreads();
    if (tid < BM) {
        int rf = flags[b * LLEN + p0 + tid];
        s_rf[tid] = rf;
        if (rf) atomicOr(&s_any, 1);
    }
    if (tid < BN) s_bias[tid] = bias[nt * BN + tid];
    __syncthreads();

    float* outbase = out + ((size_t)(b * LLEN + p0)) * DDIM + nt * BN;

    if (!s_any) {   // whole tile uncovered -> zeros
        f32x4 z = {0.f, 0.f, 0.f, 0.f};
        #pragma unroll
        for (int q = 0; q < 16; ++q) {
            int flat = q * 256 + tid;           // 128 rows x 32 float4
            int row = flat >> 5, c4 = flat & 31;
            *reinterpret_cast<f32x4*>(outbase + (size_t)row * DDIM + c4 * 4) = z;
        }
        return;
    }

    int w  = tid >> 6;
    int l  = tid & 63;
    int wr = w >> 1, wc = w & 1;     // 2x2 waves, each 64x64
    int lr = l & 15, lg = l >> 4;

    // per-thread A-staging descriptors (4 slots of 16B per k-step)
    int  useq[4];                      // bit t = tap t active for this slot's row
    const unsigned short* rowptr[4];   // featbf + row*768 + swizzled col chunk
    unsigned ldsoff[4];                // wave-uniform LDS 16B-slot base (bytes)
    #pragma unroll
    for (int q = 0; q < 4; ++q) {
        int flat = q * 256 + tid;
        int row = flat >> 3, c8 = flat & 7;
        int c8s = c8 ^ (row & 7);
        int rf = s_rf[row];
        useq[q] = ((rf >> 1) & 1) | ((rf & 1) << 1) | (((rf >> 2) & 1) << 2);
        rowptr[q] = featbf + ((size_t)(b * LLEN + p0 + row) * DDIM + c8s * 8);
        ldsoff[q] = (unsigned)(((q * 256) + (tid & 192)) * 16);
    }
    const unsigned short* WpBase = Wp + (size_t)nt * NKS * (BN * BK) + (size_t)tid * 8;

    auto stage = [&](int ks) {   // 8 loads total (4 A + 4 B), zero VGPR staging
        int tap = ks / (DDIM / BK);
        int i0  = (ks % (DDIM / BK)) * BK;
        #pragma unroll
        for (int q = 0; q < 4; ++q) {
            const unsigned short* src = ((useq[q] >> tap) & 1)
                ? rowptr[q] + (size_t)(tap - 1) * DDIM + i0
                : zeropage;
            gload_lds16(src, &As[ldsoff[q]]);
        }
        const unsigned short* bsrc = WpBase + (size_t)ks * (BN * BK);
        #pragma unroll
        for (int q = 0; q < 4; ++q)
            gload_lds16(bsrc + q * 256 * 8, &Bs[ldsoff[q]]);
    };

    f32x4 acc[4][4];
    #pragma unroll
    for (int i = 0; i < 4; ++i)
        #pragma unroll
        for (int j = 0; j < 4; ++j) acc[i][j] = (f32x4){0.f, 0.f, 0.f, 0.f};

    unsigned abase[4], aswz[4], bbase[4], bswz[4];
    #pragma unroll
    for (int fm = 0; fm < 4; ++fm) {
        int row = wr * 64 + fm * 16 + lr;
        abase[fm] = (unsigned)(row * (BK * 2) + lg * 16);
        aswz[fm]  = ((unsigned)(row & 7) << 4);
    }
    #pragma unroll
    for (int fn = 0; fn < 4; ++fn) {
        int col = wc * 64 + fn * 16 + lr;
        bbase[fn] = (unsigned)(col * (BK * 2) + lg * 16);
        bswz[fn]  = ((unsigned)(col & 7) << 4);
    }

    auto compute = [&]() {
        #pragma unroll
        for (int kc = 0; kc < 2; ++kc) {
            bf16x8 av[4], bv[4];
            #pragma unroll
            for (int fm = 0; fm < 4; ++fm)
                av[fm] = *reinterpret_cast<const bf16x8*>(As + ((abase[fm] + kc * 64) ^ aswz[fm]));
            #pragma unroll
            for (int fn = 0; fn < 4; ++fn)
                bv[fn] = *reinterpret_cast<const bf16x8*>(Bs + ((bbase[fn] + kc * 64) ^ bswz[fn]));
            #pragma unroll
            for (int fm = 0; fm < 4; ++fm)
                #pragma unroll
                for (int fn = 0; fn < 4; ++fn)
                    acc[fm][fn] = __builtin_amdgcn_mfma_f32_16x16x32_bf16(
                        av[fm], bv[fn], acc[fm][fn], 0, 0, 0);
        }
    };

    // m97-structure main loop; drain stall covered by 4 co-resident blocks.
    #pragma unroll 1
    for (int ks = 0; ks < NKS; ++ks) {
        stage(ks);
        __syncthreads();     // compiler emits vmcnt(0) drain: tile ready
        compute();
        __syncthreads();     // all waves done reading before overwrite
    }

    // ---- epilogue: bias + relu, invalid rows -> 0 ----
    #pragma unroll
    for (int fm = 0; fm < 4; ++fm) {
        #pragma unroll
        for (int fn = 0; fn < 4; ++fn) {
            int colL = wc * 64 + fn * 16 + lr;
            float bn = s_bias[colL];
            #pragma unroll
            for (int j = 0; j < 4; ++j) {
                int rowL = wr * 64 + fm * 16 + lg * 4 + j;
                int rf = s_rf[rowL];
                float v = (rf & 1) ? fmaxf(acc[fm][fn][j] + bn, 0.f) : 0.f;
                outbase[(size_t)rowL * DDIM + colL] = v;
            }
        }
    }
}

// ---------------- fallback kernel (fp32 in-loop conversion, small ws) ----------------
__global__ __launch_bounds__(256) void conv_mfma_kernel(
    const float* __restrict__ feat, const int* __restrict__ flags,
    const unsigned short* __restrict__ Wp, const float* __restrict__ bias,
    float* __restrict__ out)
{
    int nt = blockIdx.x % NTILE;
    int rb = blockIdx.x / NTILE;
    int b  = rb / (LLEN / BM);
    int p0 = (rb % (LLEN / BM)) * BM;
    int tid = threadIdx.x;

    __shared__ int s_rf[BM];
    __shared__ int s_any;
    __shared__ float s_bias[BN];
    __shared__ __align__(16) unsigned char As[BM * BK * 2];
    __shared__ __align__(16) unsigned char Bs[BK * BN * 2];

    if (tid == 0) s_any = 0;
    __syncthreads();
    if (tid < BM) {
        int rf = flags[b * LLEN + p0 + tid];
        s_rf[tid] = rf;
        if (rf) atomicOr(&s_any, 1);
    }
    if (tid < BN) s_bias[tid] = bias[nt * BN + tid];
    __syncthreads();

    float* outbase = out + ((size_t)(b * LLEN + p0)) * DDIM + nt * BN;

    if (!s_any) {
        f32x4 z = {0.f, 0.f, 0.f, 0.f};
        #pragma unroll
        for (int q = 0; q < 16; ++q) {
            int flat = q * 256 + tid;
            int row = flat >> 5, c4 = flat & 31;
            *reinterpret_cast<f32x4*>(outbase + (size_t)row * DDIM + c4 * 4) = z;
        }
        return;
    }

    int w  = tid >> 6;
    int l  = tid & 63;
    int wr = w >> 1, wc = w & 1;
    int lr = l & 15, lg = l >> 4;

    f32x4 acc[4][4];
    #pragma unroll
    for (int i = 0; i < 4; ++i)
        #pragma unroll
        for (int j = 0; j < 4; ++j) acc[i][j] = (f32x4){0.f, 0.f, 0.f, 0.f};

    unsigned abase[4], aswz[4], bbase[4], bswz[4];
    #pragma unroll
    for (int fm = 0; fm < 4; ++fm) {
        int row = wr * 64 + fm * 16 + lr;
        abase[fm] = (unsigned)(row * (BK * 2) + lg * 16);
        aswz[fm]  = ((unsigned)(row & 7) << 4);
    }
    #pragma unroll
    for (int fn = 0; fn < 4; ++fn) {
        int col = wc * 64 + fn * 16 + lr;
        bbase[fn] = (unsigned)(col * (BK * 2) + lg * 16);
        bswz[fn]  = ((unsigned)(col & 7) << 4);
    }

    const unsigned short* WpBase = Wp + (size_t)nt * NKS * (BN * BK);

    for (int ks = 0; ks < NKS; ++ks) {
        int tap = ks / (DDIM / BK);
        int i0  = (ks % (DDIM / BK)) * BK;

        #pragma unroll
        for (int q = 0; q < 8; ++q) {
            int flat = q * 256 + tid;
            int row = flat >> 4, c4 = flat & 15;
            int rf = s_rf[row];
            int use = (tap == 0) ? ((rf >> 1) & 1) : (tap == 1) ? (rf & 1) : ((rf >> 2) & 1);
            unsigned lo = 0, hi = 0;
            if (use) {
                int p = p0 + row + tap - 1;
                const float* src = feat + ((size_t)(b * LLEN + p)) * DDIM + i0 + c4 * 4;
                f32x4 v = *reinterpret_cast<const f32x4*>(src);
                lo = (unsigned)f2bf(v.x) | ((unsigned)f2bf(v.y) << 16);
                hi = (unsigned)f2bf(v.z) | ((unsigned)f2bf(v.w) << 16);
            }
            unsigned byte = (unsigned)(row * (BK * 2) + c4 * 8);
            byte ^= ((unsigned)(row & 7) << 4);
            *reinterpret_cast<uint2*>(As + byte) = make_uint2(lo, hi);
        }

        {
            const uint4* src = reinterpret_cast<const uint4*>(WpBase + (size_t)ks * (BN * BK));
            uint4* dst = reinterpret_cast<uint4*>(Bs);
            #pragma unroll
            for (int q = 0; q < 4; ++q) {
                int f16 = q * 256 + tid;
                dst[f16] = src[f16];
            }
        }
        __syncthreads();

        #pragma unroll
        for (int kc = 0; kc < 2; ++kc) {
            bf16x8 av[4], bv[4];
            #pragma unroll
            for (int fm = 0; fm < 4; ++fm)
                av[fm] = *reinterpret_cast<const bf16x8*>(As + ((abase[fm] + kc * 64) ^ aswz[fm]));
            #pragma unroll
            for (int fn = 0; fn < 4; ++fn)
                bv[fn] = *reinterpret_cast<const bf16x8*>(Bs + ((bbase[fn] + kc * 64) ^ bswz[fn]));
            #pragma unroll
            for (int fm = 0; fm < 4; ++fm)
                #pragma unroll
                for (int fn = 0; fn < 4; ++fn)
                    acc[fm][fn] = __builtin_amdgcn_mfma_f32_16x16x32_bf16(
                        av[fm], bv[fn], acc[fm][fn], 0, 0, 0);
        }
        __syncthreads();
    }

    #pragma unroll
    for (int fm = 0; fm < 4; ++fm) {
        #pragma unroll
        for (int fn = 0; fn < 4; ++fn) {
            int colL = wc * 64 + fn * 16 + lr;
            float bn = s_bias[colL];
            #pragma unroll
            for (int j = 0; j < 4; ++j) {
                int rowL = wr * 64 + fm * 16 + lg * 4 + j;
                int rf = s_rf[rowL];
                float v = (rf & 1) ? fmaxf(acc[fm][fn][j] + bn, 0.f) : 0.f;
                outbase[(size_t)rowL * DDIM + colL] = v;
            }
        }
    }
}

extern "C" void kernel_launch(void* const* d_in, const int* in_sizes, int n_in,
                              void* d_out, int out_size, void* d_ws, size_t ws_size,
                              hipStream_t stream) {
    const float* feat = (const float*)d_in[0];        // [B,L,D] fp32
    const int*   lens = (const int*)d_in[1];          // [B,C] int32
    const float* cw   = (const float*)d_in[2];        // [D,D,3] fp32
    const float* cb   = (const float*)d_in[3];        // [D] fp32
    float* outp = (float*)d_out;

    char* ws = (char*)d_ws;
    int* flags = (int*)(ws + FLAGS_OFF);
    unsigned short* Wp = (unsigned short*)(ws + WP_OFF);
    unsigned int* zeropage = (unsigned int*)(ws + ZP_OFF);

    packw2_kernel<<<(NTILE * NKS * BN * 8 + 255) / 256 + 1, 256, 0, stream>>>(cw, Wp, zeropage);

    if (ws_size >= WS_NEED) {
        unsigned short* featbf = (unsigned short*)(ws + FB_OFF);
        meta_cvt_kernel<<<NB * CVT_SLICES, 256, 0, stream>>>(lens, feat, flags, featbf);
        conv_mfma3_kernel<<<NRB * NTILE, 256, 0, stream>>>(featbf, flags, Wp, cb,
                                                           (const unsigned short*)zeropage, outp);
    } else {
        meta_kernel<<<NB, CCH, 0, stream>>>(lens, flags);
        conv_mfma_kernel<<<NRB * NTILE, 256, 0, stream>>>(feat, flags, Wp, cb, outp);
    }
}